// Round 3
// baseline (229.283 us; speedup 1.0000x reference)
//
#include <hip/hip_runtime.h>
#include <hip/hip_fp8.h>
#include <math.h>

#define NB 8
#define CI 512
#define CO 256
#define NN 2048           // T*H*W
#define SCALE 0.0625f     // 1/sqrt(CO), applied inside exp in attention
#define SPLIT 4           // KV split factor

typedef __bf16 v8bf __attribute__((ext_vector_type(8)));
typedef __bf16 v4bf __attribute__((ext_vector_type(4)));
typedef float  f32x4  __attribute__((ext_vector_type(4)));
typedef float  f32x16 __attribute__((ext_vector_type(16)));
typedef unsigned char u8;
typedef long i64t;

static __device__ __forceinline__ u8 to_fp8(float x) {
    __hip_fp8_e4m3 t(x);           // OCP e4m3fn on gfx950
    return (u8)t.__x;
}

static __device__ __forceinline__ i64t pack64(unsigned lo, unsigned hi) {
    return (i64t)(((unsigned long long)hi << 32) | (unsigned long long)lo);
}

// ---------------------------------------------------------------------------
// Fused projections v2: k = key_w@x (fp8 [B,N,Co]), v = val_w@x (fp8 [B,Co,N]),
// q = query_w@query (fp8 [B,N,Co]).
// Tile 64n x 64co (grid 32x4x8 = 1024 blocks -> 4 blocks/CU), K-chunk 32.
// T14: next chunk prefetched into registers under the MFMA phase (the round-1
// structure exposed full load latency every chunk: MfmaUtil 10.7 / VALU 22.8 /
// HBM 15 / Occ 17.6 -> latency-bound). T5 setprio around MFMA cluster.
// LDS 25.6 KB, 2 barriers/chunk, staging writes bank-uniform (20-dw pitch).
// ---------------------------------------------------------------------------
__global__ __launch_bounds__(256, 3)
void proj3_kernel(const float* __restrict__ x, const float* __restrict__ query,
                  const float* __restrict__ wk, const float* __restrict__ bk,
                  const float* __restrict__ wv, const float* __restrict__ bv,
                  const float* __restrict__ wq, const float* __restrict__ bq,
                  u8* __restrict__ outK, u8* __restrict__ outV, u8* __restrict__ outQ)
{
    const int b = blockIdx.z, n0 = blockIdx.x * 64, co0 = blockIdx.y * 64;
    const int tid = threadIdx.x;
    const int wave = tid >> 6, lane = tid & 63;
    const int l16 = lane & 15, quad = lane >> 4;
    const int wn = wave & 1, wc = wave >> 1;

    __shared__ __bf16 Xt[64][40];
    __shared__ __bf16 Qt[64][40];
    __shared__ __bf16 Wks[64][40];
    __shared__ __bf16 Wvs[64][40];
    __shared__ __bf16 Wqs[64][40];

    // staging coords: thread owns n = tid&63, k-group xc = tid>>6 (8 k each)
    const int xn = tid & 63;
    const int xc = tid >> 6;
    const float* xp = x     + (size_t)b * CI * NN + (size_t)xc * 8 * NN + n0 + xn;
    const float* qp = query + (size_t)b * CI * NN + (size_t)xc * 8 * NN + n0 + xn;

    // weight staging coords: g-th float4: co = (tid+256g)>>3, cq = (tid+256g)&7
    const int wco0 = tid >> 3, wcq = tid & 7;   // g=0
    const int wco1 = (tid + 256) >> 3, wcq1 = tid & 7;   // g=1 (cq same: +256 = +32 rows)
    const float* wkp0 = wk + (size_t)(co0 + wco0) * CI + wcq * 4;
    const float* wvp0 = wv + (size_t)(co0 + wco0) * CI + wcq * 4;
    const float* wqp0 = wq + (size_t)(co0 + wco0) * CI + wcq * 4;
    const float* wkp1 = wk + (size_t)(co0 + wco1) * CI + wcq1 * 4;
    const float* wvp1 = wv + (size_t)(co0 + wco1) * CI + wcq1 * 4;
    const float* wqp1 = wq + (size_t)(co0 + wco1) * CI + wcq1 * 4;

    f32x4 acck[2][2], accv[2][2], accq[2][2];
    #pragma unroll
    for (int i = 0; i < 2; ++i)
        #pragma unroll
        for (int j = 0; j < 2; ++j) {
            acck[i][j] = f32x4{0,0,0,0}; accv[j][i] = f32x4{0,0,0,0};
            accq[i][j] = f32x4{0,0,0,0};
        }

    // T14 prologue: prefetch chunk 0 into registers
    float xz[8], qz[8];
    float4 wkf[2], wvf[2], wqf[2];
    #pragma unroll
    for (int j = 0; j < 8; ++j) { xz[j] = xp[(size_t)j * NN]; qz[j] = qp[(size_t)j * NN]; }
    wkf[0] = *(const float4*)(wkp0); wvf[0] = *(const float4*)(wvp0); wqf[0] = *(const float4*)(wqp0);
    wkf[1] = *(const float4*)(wkp1); wvf[1] = *(const float4*)(wvp1); wqf[1] = *(const float4*)(wqp1);

    for (int k0 = 0; k0 < CI; k0 += 32) {
        // registers -> LDS (convert f32 -> bf16 at write time)
        {
            v8bf z, w;
            #pragma unroll
            for (int j = 0; j < 8; ++j) { z[j] = (__bf16)xz[j]; w[j] = (__bf16)qz[j]; }
            *(v8bf*)&Xt[xn][xc * 8] = z;
            *(v8bf*)&Qt[xn][xc * 8] = w;
            *(v4bf*)&Wks[wco0][wcq * 4]  = v4bf{(__bf16)wkf[0].x, (__bf16)wkf[0].y, (__bf16)wkf[0].z, (__bf16)wkf[0].w};
            *(v4bf*)&Wvs[wco0][wcq * 4]  = v4bf{(__bf16)wvf[0].x, (__bf16)wvf[0].y, (__bf16)wvf[0].z, (__bf16)wvf[0].w};
            *(v4bf*)&Wqs[wco0][wcq * 4]  = v4bf{(__bf16)wqf[0].x, (__bf16)wqf[0].y, (__bf16)wqf[0].z, (__bf16)wqf[0].w};
            *(v4bf*)&Wks[wco1][wcq1 * 4] = v4bf{(__bf16)wkf[1].x, (__bf16)wkf[1].y, (__bf16)wkf[1].z, (__bf16)wkf[1].w};
            *(v4bf*)&Wvs[wco1][wcq1 * 4] = v4bf{(__bf16)wvf[1].x, (__bf16)wvf[1].y, (__bf16)wvf[1].z, (__bf16)wvf[1].w};
            *(v4bf*)&Wqs[wco1][wcq1 * 4] = v4bf{(__bf16)wqf[1].x, (__bf16)wqf[1].y, (__bf16)wqf[1].z, (__bf16)wqf[1].w};
        }
        __syncthreads();

        // T14: issue next chunk's loads; latency hides under frag reads + MFMA
        if (k0 + 32 < CI) {
            const size_t koff = (size_t)(k0 + 32) * NN;
            #pragma unroll
            for (int j = 0; j < 8; ++j) {
                xz[j] = xp[koff + (size_t)j * NN];
                qz[j] = qp[koff + (size_t)j * NN];
            }
            wkf[0] = *(const float4*)(wkp0 + k0 + 32); wvf[0] = *(const float4*)(wvp0 + k0 + 32);
            wqf[0] = *(const float4*)(wqp0 + k0 + 32);
            wkf[1] = *(const float4*)(wkp1 + k0 + 32); wvf[1] = *(const float4*)(wvp1 + k0 + 32);
            wqf[1] = *(const float4*)(wqp1 + k0 + 32);
        }

        v8bf ax[2], aqx[2], bkf[2], bqf[2], bvf[2];
        #pragma unroll
        for (int i = 0; i < 2; ++i) {
            ax[i]  = *(const v8bf*)&Xt[wn * 32 + i * 16 + l16][quad * 8];
            aqx[i] = *(const v8bf*)&Qt[wn * 32 + i * 16 + l16][quad * 8];
        }
        #pragma unroll
        for (int j = 0; j < 2; ++j) {
            bkf[j] = *(const v8bf*)&Wks[wc * 32 + j * 16 + l16][quad * 8];
            bqf[j] = *(const v8bf*)&Wqs[wc * 32 + j * 16 + l16][quad * 8];
            bvf[j] = *(const v8bf*)&Wvs[wc * 32 + j * 16 + l16][quad * 8];
        }
        __builtin_amdgcn_s_setprio(1);
        #pragma unroll
        for (int i = 0; i < 2; ++i)
            #pragma unroll
            for (int j = 0; j < 2; ++j) {
                acck[i][j] = __builtin_amdgcn_mfma_f32_16x16x32_bf16(ax[i],  bkf[j], acck[i][j], 0, 0, 0);
                accq[i][j] = __builtin_amdgcn_mfma_f32_16x16x32_bf16(aqx[i], bqf[j], accq[i][j], 0, 0, 0);
                accv[j][i] = __builtin_amdgcn_mfma_f32_16x16x32_bf16(bvf[j], ax[i],  accv[j][i], 0, 0, 0);
            }
        __builtin_amdgcn_s_setprio(0);
        __syncthreads();
    }

    // k and q epilogues: D[m=n][col=co], fp8 out
    #pragma unroll
    for (int i = 0; i < 2; ++i) {
        int n = n0 + wn * 32 + i * 16 + quad * 4;
        #pragma unroll
        for (int j = 0; j < 2; ++j) {
            int co = co0 + wc * 32 + j * 16 + l16;
            float bkk = bk[co], bqq = bq[co];
            u8* dk = outK + ((size_t)b * NN + n) * CO + co;
            u8* dq = outQ + ((size_t)b * NN + n) * CO + co;
            #pragma unroll
            for (int r = 0; r < 4; ++r) {
                dk[(size_t)r * CO] = to_fp8(acck[i][j][r] + bkk);
                dq[(size_t)r * CO] = to_fp8(accq[i][j][r] + bqq);
            }
        }
    }
    // v epilogue: D[m=co][col=n]
    #pragma unroll
    for (int j = 0; j < 2; ++j) {
        int co = co0 + wc * 32 + j * 16 + quad * 4;
        #pragma unroll
        for (int r = 0; r < 4; ++r) {
            float bvv = bv[co + r];
            #pragma unroll
            for (int i = 0; i < 2; ++i) {
                int n = n0 + wn * 32 + i * 16 + l16;
                outV[((size_t)b * CO + co + r) * NN + n] = to_fp8(accv[j][i][r] + bvv);
            }
        }
    }
}

// ---------------------------------------------------------------------------
// Flash attention v2: swapped-operand QK^T (D[kv][q]) keeps each lane's full
// P row in registers -> in-register fp8 pack (cvt_pk_fp8) feeds PV's A-frag
// DIRECTLY (k-slot permutation absorbed into the V LDS dword order at staging:
// middle-dword swap). No duplicated QK^T, no P LDS round-trip, no cross-lane.
// Each wave: 32 q-rows x full Co=256 (acc 8x f32x16 = 128 VGPR). Block = 128q,
// 4 waves. LDS qword-padded: Ks pitch 264B / Vt pitch 72B -> 2-way max (free).
// T14 async stage split (issue global loads under compute), T5 setprio.
// ---------------------------------------------------------------------------
__global__ __launch_bounds__(256, 2)
void attn_kernel(const u8* __restrict__ kT, const u8* __restrict__ qT,
                 const u8* __restrict__ vT2, __bf16* __restrict__ Opart,
                 float* __restrict__ lbuf)
{
    const int b = blockIdx.z, part = blockIdx.y, n0 = blockIdx.x * 128;
    const int tid = threadIdx.x;
    const int wave = tid >> 6, lane = tid & 63;
    const int l32 = lane & 31, hs = lane >> 5;

    __shared__ i64t Ks8[64][33];    // [kv][c qwords], pitch 264 B (66 dw: 2-way)
    __shared__ i64t Vt8[256][9];    // [co][kv qwords, dword-interleaved], 72 B

    const int start = part * (NN / SPLIT);        // 512 kv per part
    const u8* Ksrc = qT + ((size_t)b * NN + start) * CO;   // attn-K rows [kv][c]
    const u8* Vsrc = vT2 + (size_t)b * CO * NN + start;    // [co][kv]

    // resident Q fragments (B operand): lane holds Q[q=l32][c=s*16+hs*8 ..+7]
    i64t aq[16];
    {
        const u8* qrow = kT + ((size_t)b * NN + n0 + wave * 32 + l32) * CO + hs * 8;
        #pragma unroll
        for (int s = 0; s < 16; ++s) aq[s] = *(const i64t*)(qrow + s * 16);
    }

    f32x16 acc[8];
    #pragma unroll
    for (int t = 0; t < 8; ++t)
        #pragma unroll
        for (int r = 0; r < 16; ++r) acc[t][r] = 0.f;
    float lp = 0.f;

    // T14: stage tile 0 into registers
    int4 kx[4], vx[4];
    #pragma unroll
    for (int r2 = 0; r2 < 4; ++r2) {
        int c = tid + 256 * r2;
        kx[r2] = *(const int4*)(Ksrc + (size_t)(c >> 4) * CO + (c & 15) * 16);
        vx[r2] = *(const int4*)(Vsrc + (size_t)(c >> 2) * NN + (c & 3) * 16);
    }

    for (int it = 0; it < NN / SPLIT / 64; ++it) {
        // registers -> LDS (split b64 writes; V gets middle-dword swap so that
        // row qword 2g   = kv{16g+0..3, 16g+8..11}  (PV slots 0-7,  hs=0)
        //     qword 2g+1 = kv{16g+4..7, 16g+12..15} (PV slots 8-15, hs=1)
        #pragma unroll
        for (int r2 = 0; r2 < 4; ++r2) {
            int c = tid + 256 * r2;
            i64t* kd = &Ks8[c >> 4][(c & 15) * 2];
            kd[0] = *(const i64t*)&kx[r2].x;
            kd[1] = *(const i64t*)&kx[r2].z;
            i64t* vd = &Vt8[c >> 2][(c & 3) * 2];
            vd[0] = pack64((unsigned)vx[r2].x, (unsigned)vx[r2].z);
            vd[1] = pack64((unsigned)vx[r2].y, (unsigned)vx[r2].w);
        }
        __syncthreads();

        // issue next tile's global loads; latency hides under QK^T + PV
        if (it + 1 < NN / SPLIT / 64) {
            const u8* Kit = Ksrc + (size_t)(it + 1) * 64 * CO;
            const u8* Vit = Vsrc + (it + 1) * 64;
            #pragma unroll
            for (int r2 = 0; r2 < 4; ++r2) {
                int c = tid + 256 * r2;
                kx[r2] = *(const int4*)(Kit + (size_t)(c >> 4) * CO + (c & 15) * 16);
                vx[r2] = *(const int4*)(Vit + (size_t)(c >> 2) * NN + (c & 3) * 16);
            }
        }

        // S^T = K Q^T per 32-kv subtile: D[kv][q=l32]; softmax lane-local
        int dpk[8];
        #pragma unroll
        for (int sub = 0; sub < 2; ++sub) {
            f32x16 sacc;
            #pragma unroll
            for (int r = 0; r < 16; ++r) sacc[r] = 0.f;
            __builtin_amdgcn_s_setprio(1);
            #pragma unroll
            for (int s = 0; s < 16; ++s) {
                i64t kf = Ks8[sub * 32 + l32][s * 2 + hs];
                sacc = __builtin_amdgcn_mfma_f32_32x32x16_fp8_fp8(kf, aq[s], sacc, 0, 0, 0);
            }
            __builtin_amdgcn_s_setprio(0);
            // stats-free softmax: p = exp(S/16); reg r -> kv = (r&3)+8*(r>>2)+4*hs
            #pragma unroll
            for (int r = 0; r < 16; ++r) {
                sacc[r] = __expf(sacc[r] * SCALE);
                lp += sacc[r];
            }
            #pragma unroll
            for (int g = 0; g < 4; ++g) {
                int lo = __builtin_amdgcn_cvt_pk_fp8_f32(sacc[4*g+0], sacc[4*g+1], 0, false);
                dpk[sub * 4 + g] = __builtin_amdgcn_cvt_pk_fp8_f32(sacc[4*g+2], sacc[4*g+3], lo, true);
            }
        }
        // PV A-frags: chunk c (16 kv) = {dpk[2c], dpk[2c+1]} — already slot-ordered
        i64t pa[4];
        #pragma unroll
        for (int c = 0; c < 4; ++c)
            pa[c] = pack64((unsigned)dpk[2 * c], (unsigned)dpk[2 * c + 1]);

        __builtin_amdgcn_s_setprio(1);
        #pragma unroll
        for (int t = 0; t < 8; ++t) {
            #pragma unroll
            for (int c = 0; c < 4; ++c) {
                i64t bvf = Vt8[t * 32 + l32][c * 2 + hs];
                acc[t] = __builtin_amdgcn_mfma_f32_32x32x16_fp8_fp8(pa[c], bvf, acc[t], 0, 0, 0);
            }
        }
        __builtin_amdgcn_s_setprio(0);
        __syncthreads();   // LDS reads done before next tile's writes
    }

    // row sums: lane holds half of q-row l32's kv mass; partner is lane^32
    lp += __shfl_xor(lp, 32);
    if (hs == 0)
        lbuf[(size_t)(part * NB + b) * NN + n0 + wave * 32 + l32] = lp;

    // store unnormalized bf16 partial: D[q over regs][co = t*32 + l32]
    const size_t qbase = (size_t)(part * NB + b) * NN + n0 + wave * 32;
    #pragma unroll
    for (int t = 0; t < 8; ++t)
        #pragma unroll
        for (int r = 0; r < 16; ++r) {
            int row = (r & 3) + 8 * (r >> 2) + 4 * hs;
            Opart[(qbase + row) * CO + t * 32 + l32] = (__bf16)acc[t][r];
        }
}

// ---------------------------------------------------------------------------
// Merge SPLIT partials: O = (sum O_i) / (sum l_i) -> ob bf16 [B,N,Co]
// ---------------------------------------------------------------------------
__global__ __launch_bounds__(256)
void merge_kernel(const __bf16* __restrict__ Opart, const float* __restrict__ lbuf,
                  __bf16* __restrict__ ob)
{
    int gid = blockIdx.x * 256 + threadIdx.x;
    int chunk = gid & 31;
    int row = gid >> 5;        // b*NN + n
    float ls = 0.f;
    #pragma unroll
    for (int p = 0; p < SPLIT; ++p) ls += lbuf[(size_t)p * NB * NN + row];
    float inv = 1.0f / ls;
    float o[8] = {0,0,0,0,0,0,0,0};
    #pragma unroll
    for (int p = 0; p < SPLIT; ++p) {
        v8bf v = *(const v8bf*)(Opart + ((size_t)p * NB * NN + row) * CO + chunk * 8);
        #pragma unroll
        for (int j = 0; j < 8; ++j) o[j] += (float)v[j];
    }
    v8bf res;
    #pragma unroll
    for (int j = 0; j < 8; ++j) res[j] = (__bf16)(o[j] * inv);
    *(v8bf*)(ob + (size_t)row * CO + chunk * 8) = res;
}

// ---------------------------------------------------------------------------
// up: out[b][ci][n] = x + sc*(b2[ci] + sum_co w2[ci][co] * Z[n][co]),
// Z[n][co] = ob_flat[b][co*NN + n] (raw-reshape view). Tile 128n x 128ci.
// ---------------------------------------------------------------------------
__global__ __launch_bounds__(256)
void up_kernel(const __bf16* __restrict__ ob, const float* __restrict__ x,
               const float* __restrict__ w2, const float* __restrict__ b2,
               const float* __restrict__ scaling, float* __restrict__ out)
{
    const int b = blockIdx.z, n0 = blockIdx.x * 128, ci0 = blockIdx.y * 128;
    const int tid = threadIdx.x;
    const int wave = tid >> 6, lane = tid & 63;
    const int l16 = lane & 15, quad = lane >> 4;
    const int wn = wave & 1, wci = wave >> 1;

    __shared__ __bf16 Zt[128][40];
    __shared__ __bf16 Wt[128][40];

    const __bf16* obb = ob + (size_t)b * CO * NN;

    f32x4 acc[4][4];
    #pragma unroll
    for (int i = 0; i < 4; ++i)
        #pragma unroll
        for (int j = 0; j < 4; ++j) acc[i][j] = f32x4{0,0,0,0};

    const int zn = tid & 127, zc = tid >> 7;

    for (int k0 = 0; k0 < CO; k0 += 32) {
        #pragma unroll
        for (int g = 0; g < 2; ++g) {
            int cg = zc + g * 2;
            v8bf z;
            #pragma unroll
            for (int j = 0; j < 8; ++j)
                z[j] = obb[(size_t)(k0 + cg * 8 + j) * NN + n0 + zn];
            *(v8bf*)&Zt[zn][cg * 8] = z;
        }
        #pragma unroll
        for (int g = 0; g < 4; ++g) {
            int f = tid + 256 * g;
            int ci = f >> 3, cq = f & 7;
            float4 v = *(const float4*)(w2 + (size_t)(ci0 + ci) * CO + k0 + cq * 4);
            *(v4bf*)&Wt[ci][cq * 4] = v4bf{(__bf16)v.x, (__bf16)v.y, (__bf16)v.z, (__bf16)v.w};
        }
        __syncthreads();
        v8bf aw[4], bz[4];
        #pragma unroll
        for (int i = 0; i < 4; ++i) aw[i] = *(const v8bf*)&Wt[wci * 64 + i * 16 + l16][quad * 8];
        #pragma unroll
        for (int j = 0; j < 4; ++j) bz[j] = *(const v8bf*)&Zt[wn * 64 + j * 16 + l16][quad * 8];
        #pragma unroll
        for (int i = 0; i < 4; ++i)
            #pragma unroll
            for (int j = 0; j < 4; ++j)
                acc[i][j] = __builtin_amdgcn_mfma_f32_16x16x32_bf16(aw[i], bz[j], acc[i][j], 0, 0, 0);
        __syncthreads();
    }
    float sc = scaling[0];
    #pragma unroll
    for (int i = 0; i < 4; ++i) {
        int ci = ci0 + wci * 64 + i * 16 + quad * 4;
        #pragma unroll
        for (int r = 0; r < 4; ++r) {
            float bvv = b2[ci + r];
            #pragma unroll
            for (int j = 0; j < 4; ++j) {
                int n = n0 + wn * 64 + j * 16 + l16;
                size_t gi = ((size_t)b * CI + ci + r) * NN + n;
                out[gi] = x[gi] + sc * (acc[i][j][r] + bvv);
            }
        }
    }
}

extern "C" void kernel_launch(void* const* d_in, const int* in_sizes, int n_in,
                              void* d_out, int out_size, void* d_ws, size_t ws_size,
                              hipStream_t stream)
{
    (void)in_sizes; (void)n_in; (void)out_size; (void)ws_size;
    const float* x       = (const float*)d_in[0];
    const float* query   = (const float*)d_in[1];
    const float* key_w   = (const float*)d_in[2];
    const float* key_b   = (const float*)d_in[3];
    const float* val_w   = (const float*)d_in[4];
    const float* val_b   = (const float*)d_in[5];
    const float* query_w = (const float*)d_in[6];
    const float* query_b = (const float*)d_in[7];
    const float* up_w    = (const float*)d_in[8];
    const float* up_b    = (const float*)d_in[9];
    const float* scaling = (const float*)d_in[10];
    float* out = (float*)d_out;

    const size_t TEN = (size_t)NB * NN * CO;   // 4,194,304 elements
    u8* kT  = (u8*)d_ws;                       // [B,N,Co] fp8 (key proj = attn Q)
    u8* qT  = kT + TEN;                        // [B,N,Co] fp8 (query proj = attn K)
    u8* vT2 = qT + TEN;                        // [B,Co,N] fp8
    __bf16* ob    = (__bf16*)(vT2 + TEN);      // [B,N,Co] bf16
    __bf16* Opart = ob + TEN;                  // [SPLIT,B,N,Co] bf16
    float*  lbuf  = (float*)(Opart + (size_t)SPLIT * TEN);  // [SPLIT,B,N]

    dim3 blk(256);
    proj3_kernel<<<dim3(NN / 64, CO / 64, NB), blk, 0, stream>>>(
        x, query, key_w, key_b, val_w, val_b, query_w, query_b, kT, vT2, qT);
    attn_kernel<<<dim3(NN / 128, SPLIT, NB), blk, 0, stream>>>(kT, qT, vT2, Opart, lbuf);
    merge_kernel<<<dim3((NB * NN * CO / 8) / 256), blk, 0, stream>>>(Opart, lbuf, ob);
    up_kernel<<<dim3(NN / 128, CI / 128, NB), blk, 0, stream>>>(ob, x, up_w, up_b, scaling, out);
}

// Round 4
// 217.135 us; speedup vs baseline: 1.0560x; 1.0560x over previous
//
#include <hip/hip_runtime.h>
#include <hip/hip_fp8.h>
#include <math.h>

#define NB 8
#define CI 512
#define CO 256
#define NN 2048           // T*H*W
#define SCALE 0.0625f     // 1/sqrt(CO), applied inside exp in attention
#define SPLIT 4           // KV split factor

typedef __bf16 v8bf __attribute__((ext_vector_type(8)));
typedef __bf16 v4bf __attribute__((ext_vector_type(4)));
typedef float  f32x4  __attribute__((ext_vector_type(4)));
typedef float  f32x16 __attribute__((ext_vector_type(16)));
typedef unsigned char u8;
typedef long i64t;

static __device__ __forceinline__ u8 to_fp8(float x) {
    __hip_fp8_e4m3 t(x);           // OCP e4m3fn on gfx950
    return (u8)t.__x;
}

static __device__ __forceinline__ i64t pack64(unsigned lo, unsigned hi) {
    return (i64t)(((unsigned long long)hi << 32) | (unsigned long long)lo);
}

// ---------------------------------------------------------------------------
// Fused projections v3: round-1 geometry (tile 128n x 64co, K-chunk 32,
// 24 MFMA per barrier pair, grid 512) + two surgical fixes:
//  (a) T14 register prefetch of chunk k+1 issued under chunk k's MFMA cluster
//      (launch_bounds(256,2): 256-VGPR budget, prefetch set stays live).
//  (b) XOR-swizzle on Xt/Qt staging columns: pitch 20 dw made rows n,n+8
//      alias banks -> 8-way ds_write_b128 conflict; col^=((n>>3)&3) spreads
//      rows across the four 16B slots (write 2-way = free, read unchanged).
// ---------------------------------------------------------------------------
__global__ __launch_bounds__(256, 2)
void proj3_kernel(const float* __restrict__ x, const float* __restrict__ query,
                  const float* __restrict__ wk, const float* __restrict__ bk,
                  const float* __restrict__ wv, const float* __restrict__ bv,
                  const float* __restrict__ wq, const float* __restrict__ bq,
                  u8* __restrict__ outK, u8* __restrict__ outV, u8* __restrict__ outQ)
{
    const int b = blockIdx.z, n0 = blockIdx.x * 128, co0 = blockIdx.y * 64;
    const int tid = threadIdx.x;
    const int wave = tid >> 6, lane = tid & 63;
    const int l16 = lane & 15, quad = lane >> 4;
    const int wn = wave & 1, wc = wave >> 1;

    __shared__ __bf16 Xt[128][40];
    __shared__ __bf16 Qt[128][40];
    __shared__ __bf16 Wks[64][40];
    __shared__ __bf16 Wvs[64][40];
    __shared__ __bf16 Wqs[64][40];

    // staging coords: thread owns n = tid&127, k-half xc = tid>>7 (2 groups of 8)
    const int xn = tid & 127;
    const int xc = tid >> 7;
    const int xsw = (xn >> 3) & 3;          // write swizzle selector
    const float* xp = x     + (size_t)b * CI * NN + n0 + xn;
    const float* qp = query + (size_t)b * CI * NN + n0 + xn;

    // weight staging: g-th float4: co = (tid+256g)>>3, cq = tid&7
    const int wco0 = tid >> 3, wcq = tid & 7;
    const int wco1 = wco0 + 32;
    const float* wkp0 = wk + (size_t)(co0 + wco0) * CI + wcq * 4;
    const float* wvp0 = wv + (size_t)(co0 + wco0) * CI + wcq * 4;
    const float* wqp0 = wq + (size_t)(co0 + wco0) * CI + wcq * 4;
    const float* wkp1 = wk + (size_t)(co0 + wco1) * CI + wcq * 4;
    const float* wvp1 = wv + (size_t)(co0 + wco1) * CI + wcq * 4;
    const float* wqp1 = wq + (size_t)(co0 + wco1) * CI + wcq * 4;

    f32x4 acck[4][2], accv[2][4], accq[4][2];
    #pragma unroll
    for (int i = 0; i < 4; ++i)
        #pragma unroll
        for (int j = 0; j < 2; ++j) {
            acck[i][j] = f32x4{0,0,0,0}; accv[j][i] = f32x4{0,0,0,0};
            accq[i][j] = f32x4{0,0,0,0};
        }

    // T14 prologue: prefetch chunk 0 into registers
    float xz[2][8], qz[2][8];
    float4 wkf[2], wvf[2], wqf[2];
    #pragma unroll
    for (int g = 0; g < 2; ++g) {
        const int cg = xc + g * 2;
        #pragma unroll
        for (int j = 0; j < 8; ++j) {
            xz[g][j] = xp[(size_t)(cg * 8 + j) * NN];
            qz[g][j] = qp[(size_t)(cg * 8 + j) * NN];
        }
    }
    wkf[0] = *(const float4*)(wkp0); wvf[0] = *(const float4*)(wvp0); wqf[0] = *(const float4*)(wqp0);
    wkf[1] = *(const float4*)(wkp1); wvf[1] = *(const float4*)(wvp1); wqf[1] = *(const float4*)(wqp1);

    for (int k0 = 0; k0 < CI; k0 += 32) {
        // registers -> LDS (cvt f32->bf16 at write; swizzled cols for Xt/Qt)
        #pragma unroll
        for (int g = 0; g < 2; ++g) {
            const int cg = xc + g * 2;
            const int col = (cg ^ xsw) * 8;
            v8bf z, w;
            #pragma unroll
            for (int j = 0; j < 8; ++j) { z[j] = (__bf16)xz[g][j]; w[j] = (__bf16)qz[g][j]; }
            *(v8bf*)&Xt[xn][col] = z;
            *(v8bf*)&Qt[xn][col] = w;
        }
        *(v4bf*)&Wks[wco0][wcq * 4] = v4bf{(__bf16)wkf[0].x, (__bf16)wkf[0].y, (__bf16)wkf[0].z, (__bf16)wkf[0].w};
        *(v4bf*)&Wvs[wco0][wcq * 4] = v4bf{(__bf16)wvf[0].x, (__bf16)wvf[0].y, (__bf16)wvf[0].z, (__bf16)wvf[0].w};
        *(v4bf*)&Wqs[wco0][wcq * 4] = v4bf{(__bf16)wqf[0].x, (__bf16)wqf[0].y, (__bf16)wqf[0].z, (__bf16)wqf[0].w};
        *(v4bf*)&Wks[wco1][wcq * 4] = v4bf{(__bf16)wkf[1].x, (__bf16)wkf[1].y, (__bf16)wkf[1].z, (__bf16)wkf[1].w};
        *(v4bf*)&Wvs[wco1][wcq * 4] = v4bf{(__bf16)wvf[1].x, (__bf16)wvf[1].y, (__bf16)wvf[1].z, (__bf16)wvf[1].w};
        *(v4bf*)&Wqs[wco1][wcq * 4] = v4bf{(__bf16)wqf[1].x, (__bf16)wqf[1].y, (__bf16)wqf[1].z, (__bf16)wqf[1].w};
        __syncthreads();

        // T14: issue next chunk's loads; latency hides under frag reads + MFMA
        if (k0 + 32 < CI) {
            const size_t koff = (size_t)(k0 + 32) * NN;
            #pragma unroll
            for (int g = 0; g < 2; ++g) {
                const int cg = xc + g * 2;
                #pragma unroll
                for (int j = 0; j < 8; ++j) {
                    xz[g][j] = xp[koff + (size_t)(cg * 8 + j) * NN];
                    qz[g][j] = qp[koff + (size_t)(cg * 8 + j) * NN];
                }
            }
            wkf[0] = *(const float4*)(wkp0 + k0 + 32); wvf[0] = *(const float4*)(wvp0 + k0 + 32);
            wqf[0] = *(const float4*)(wqp0 + k0 + 32);
            wkf[1] = *(const float4*)(wkp1 + k0 + 32); wvf[1] = *(const float4*)(wvp1 + k0 + 32);
            wqf[1] = *(const float4*)(wqp1 + k0 + 32);
        }

        v8bf ax[4], aqx[4], bkf[2], bqf[2], bvf2[2];
        #pragma unroll
        for (int i = 0; i < 4; ++i) {
            const int row = wn * 64 + i * 16 + l16;
            const int col = (quad ^ ((row >> 3) & 3)) * 8;
            ax[i]  = *(const v8bf*)&Xt[row][col];
            aqx[i] = *(const v8bf*)&Qt[row][col];
        }
        #pragma unroll
        for (int j = 0; j < 2; ++j) {
            bkf[j]  = *(const v8bf*)&Wks[wc * 32 + j * 16 + l16][quad * 8];
            bqf[j]  = *(const v8bf*)&Wqs[wc * 32 + j * 16 + l16][quad * 8];
            bvf2[j] = *(const v8bf*)&Wvs[wc * 32 + j * 16 + l16][quad * 8];
        }
        __builtin_amdgcn_s_setprio(1);
        #pragma unroll
        for (int i = 0; i < 4; ++i)
            #pragma unroll
            for (int j = 0; j < 2; ++j) {
                acck[i][j] = __builtin_amdgcn_mfma_f32_16x16x32_bf16(ax[i],  bkf[j], acck[i][j], 0, 0, 0);
                accq[i][j] = __builtin_amdgcn_mfma_f32_16x16x32_bf16(aqx[i], bqf[j], accq[i][j], 0, 0, 0);
            }
        #pragma unroll
        for (int j = 0; j < 2; ++j)
            #pragma unroll
            for (int i = 0; i < 4; ++i)
                accv[j][i] = __builtin_amdgcn_mfma_f32_16x16x32_bf16(bvf2[j], ax[i], accv[j][i], 0, 0, 0);
        __builtin_amdgcn_s_setprio(0);
        __syncthreads();
    }

    // k and q epilogues: D[m=n][col=co], fp8 out
    #pragma unroll
    for (int i = 0; i < 4; ++i) {
        int n = n0 + wn * 64 + i * 16 + quad * 4;
        #pragma unroll
        for (int j = 0; j < 2; ++j) {
            int co = co0 + wc * 32 + j * 16 + l16;
            float bkk = bk[co], bqq = bq[co];
            u8* dk = outK + ((size_t)b * NN + n) * CO + co;
            u8* dq = outQ + ((size_t)b * NN + n) * CO + co;
            #pragma unroll
            for (int r = 0; r < 4; ++r) {
                dk[(size_t)r * CO] = to_fp8(acck[i][j][r] + bkk);
                dq[(size_t)r * CO] = to_fp8(accq[i][j][r] + bqq);
            }
        }
    }
    // v epilogue: D[m=co][col=n]
    #pragma unroll
    for (int j = 0; j < 2; ++j) {
        int co = co0 + wc * 32 + j * 16 + quad * 4;
        #pragma unroll
        for (int r = 0; r < 4; ++r) {
            float bvv = bv[co + r];
            #pragma unroll
            for (int i = 0; i < 4; ++i) {
                int n = n0 + wn * 64 + i * 16 + l16;
                outV[((size_t)b * CO + co + r) * NN + n] = to_fp8(accv[j][i][r] + bvv);
            }
        }
    }
}

// ---------------------------------------------------------------------------
// Flash attention v2: swapped-operand QK^T (D[kv][q]) keeps each lane's full
// P row in registers -> in-register fp8 pack (cvt_pk_fp8) feeds PV's A-frag
// DIRECTLY (k-slot permutation absorbed into the V LDS dword order at staging:
// middle-dword swap). No duplicated QK^T, no P LDS round-trip, no cross-lane.
// Each wave: 32 q-rows x full Co=256 (acc 8x f32x16 = 128 VGPR). Block = 128q,
// 4 waves. LDS qword-padded: Ks pitch 264B / Vt pitch 72B -> 2-way max (free).
// T14 async stage split (issue global loads under compute), T5 setprio.
// ---------------------------------------------------------------------------
__global__ __launch_bounds__(256, 2)
void attn_kernel(const u8* __restrict__ kT, const u8* __restrict__ qT,
                 const u8* __restrict__ vT2, __bf16* __restrict__ Opart,
                 float* __restrict__ lbuf)
{
    const int b = blockIdx.z, part = blockIdx.y, n0 = blockIdx.x * 128;
    const int tid = threadIdx.x;
    const int wave = tid >> 6, lane = tid & 63;
    const int l32 = lane & 31, hs = lane >> 5;

    __shared__ i64t Ks8[64][33];    // [kv][c qwords], pitch 264 B (66 dw: 2-way)
    __shared__ i64t Vt8[256][9];    // [co][kv qwords, dword-interleaved], 72 B

    const int start = part * (NN / SPLIT);        // 512 kv per part
    const u8* Ksrc = qT + ((size_t)b * NN + start) * CO;   // attn-K rows [kv][c]
    const u8* Vsrc = vT2 + (size_t)b * CO * NN + start;    // [co][kv]

    // resident Q fragments (B operand): lane holds Q[q=l32][c=s*16+hs*8 ..+7]
    i64t aq[16];
    {
        const u8* qrow = kT + ((size_t)b * NN + n0 + wave * 32 + l32) * CO + hs * 8;
        #pragma unroll
        for (int s = 0; s < 16; ++s) aq[s] = *(const i64t*)(qrow + s * 16);
    }

    f32x16 acc[8];
    #pragma unroll
    for (int t = 0; t < 8; ++t)
        #pragma unroll
        for (int r = 0; r < 16; ++r) acc[t][r] = 0.f;
    float lp = 0.f;

    // T14: stage tile 0 into registers
    int4 kx[4], vx[4];
    #pragma unroll
    for (int r2 = 0; r2 < 4; ++r2) {
        int c = tid + 256 * r2;
        kx[r2] = *(const int4*)(Ksrc + (size_t)(c >> 4) * CO + (c & 15) * 16);
        vx[r2] = *(const int4*)(Vsrc + (size_t)(c >> 2) * NN + (c & 3) * 16);
    }

    for (int it = 0; it < NN / SPLIT / 64; ++it) {
        // registers -> LDS (split b64 writes; V gets middle-dword swap so that
        // row qword 2g   = kv{16g+0..3, 16g+8..11}  (PV slots 0-7,  hs=0)
        //     qword 2g+1 = kv{16g+4..7, 16g+12..15} (PV slots 8-15, hs=1)
        #pragma unroll
        for (int r2 = 0; r2 < 4; ++r2) {
            int c = tid + 256 * r2;
            i64t* kd = &Ks8[c >> 4][(c & 15) * 2];
            kd[0] = *(const i64t*)&kx[r2].x;
            kd[1] = *(const i64t*)&kx[r2].z;
            i64t* vd = &Vt8[c >> 2][(c & 3) * 2];
            vd[0] = pack64((unsigned)vx[r2].x, (unsigned)vx[r2].z);
            vd[1] = pack64((unsigned)vx[r2].y, (unsigned)vx[r2].w);
        }
        __syncthreads();

        // issue next tile's global loads; latency hides under QK^T + PV
        if (it + 1 < NN / SPLIT / 64) {
            const u8* Kit = Ksrc + (size_t)(it + 1) * 64 * CO;
            const u8* Vit = Vsrc + (it + 1) * 64;
            #pragma unroll
            for (int r2 = 0; r2 < 4; ++r2) {
                int c = tid + 256 * r2;
                kx[r2] = *(const int4*)(Kit + (size_t)(c >> 4) * CO + (c & 15) * 16);
                vx[r2] = *(const int4*)(Vit + (size_t)(c >> 2) * NN + (c & 3) * 16);
            }
        }

        // S^T = K Q^T per 32-kv subtile: D[kv][q=l32]; softmax lane-local
        int dpk[8];
        #pragma unroll
        for (int sub = 0; sub < 2; ++sub) {
            f32x16 sacc;
            #pragma unroll
            for (int r = 0; r < 16; ++r) sacc[r] = 0.f;
            __builtin_amdgcn_s_setprio(1);
            #pragma unroll
            for (int s = 0; s < 16; ++s) {
                i64t kf = Ks8[sub * 32 + l32][s * 2 + hs];
                sacc = __builtin_amdgcn_mfma_f32_32x32x16_fp8_fp8(kf, aq[s], sacc, 0, 0, 0);
            }
            __builtin_amdgcn_s_setprio(0);
            // stats-free softmax: p = exp(S/16); reg r -> kv = (r&3)+8*(r>>2)+4*hs
            #pragma unroll
            for (int r = 0; r < 16; ++r) {
                sacc[r] = __expf(sacc[r] * SCALE);
                lp += sacc[r];
            }
            #pragma unroll
            for (int g = 0; g < 4; ++g) {
                int lo = __builtin_amdgcn_cvt_pk_fp8_f32(sacc[4*g+0], sacc[4*g+1], 0, false);
                dpk[sub * 4 + g] = __builtin_amdgcn_cvt_pk_fp8_f32(sacc[4*g+2], sacc[4*g+3], lo, true);
            }
        }
        // PV A-frags: chunk c (16 kv) = {dpk[2c], dpk[2c+1]} — already slot-ordered
        i64t pa[4];
        #pragma unroll
        for (int c = 0; c < 4; ++c)
            pa[c] = pack64((unsigned)dpk[2 * c], (unsigned)dpk[2 * c + 1]);

        __builtin_amdgcn_s_setprio(1);
        #pragma unroll
        for (int t = 0; t < 8; ++t) {
            #pragma unroll
            for (int c = 0; c < 4; ++c) {
                i64t bvf = Vt8[t * 32 + l32][c * 2 + hs];
                acc[t] = __builtin_amdgcn_mfma_f32_32x32x16_fp8_fp8(pa[c], bvf, acc[t], 0, 0, 0);
            }
        }
        __builtin_amdgcn_s_setprio(0);
        __syncthreads();   // LDS reads done before next tile's writes
    }

    // row sums: lane holds half of q-row l32's kv mass; partner is lane^32
    lp += __shfl_xor(lp, 32);
    if (hs == 0)
        lbuf[(size_t)(part * NB + b) * NN + n0 + wave * 32 + l32] = lp;

    // store unnormalized bf16 partial: D[q over regs][co = t*32 + l32]
    const size_t qbase = (size_t)(part * NB + b) * NN + n0 + wave * 32;
    #pragma unroll
    for (int t = 0; t < 8; ++t)
        #pragma unroll
        for (int r = 0; r < 16; ++r) {
            int row = (r & 3) + 8 * (r >> 2) + 4 * hs;
            Opart[(qbase + row) * CO + t * 32 + l32] = (__bf16)acc[t][r];
        }
}

// ---------------------------------------------------------------------------
// Merge SPLIT partials: O = (sum O_i) / (sum l_i) -> ob bf16 [B,N,Co]
// ---------------------------------------------------------------------------
__global__ __launch_bounds__(256)
void merge_kernel(const __bf16* __restrict__ Opart, const float* __restrict__ lbuf,
                  __bf16* __restrict__ ob)
{
    int gid = blockIdx.x * 256 + threadIdx.x;
    int chunk = gid & 31;
    int row = gid >> 5;        // b*NN + n
    float ls = 0.f;
    #pragma unroll
    for (int p = 0; p < SPLIT; ++p) ls += lbuf[(size_t)p * NB * NN + row];
    float inv = 1.0f / ls;
    float o[8] = {0,0,0,0,0,0,0,0};
    #pragma unroll
    for (int p = 0; p < SPLIT; ++p) {
        v8bf v = *(const v8bf*)(Opart + ((size_t)p * NB * NN + row) * CO + chunk * 8);
        #pragma unroll
        for (int j = 0; j < 8; ++j) o[j] += (float)v[j];
    }
    v8bf res;
    #pragma unroll
    for (int j = 0; j < 8; ++j) res[j] = (__bf16)(o[j] * inv);
    *(v8bf*)(ob + (size_t)row * CO + chunk * 8) = res;
}

// ---------------------------------------------------------------------------
// up: out[b][ci][n] = x + sc*(b2[ci] + sum_co w2[ci][co] * Z[n][co]),
// Z[n][co] = ob_flat[b][co*NN + n] (raw-reshape view). Tile 128n x 128ci.
// ---------------------------------------------------------------------------
__global__ __launch_bounds__(256)
void up_kernel(const __bf16* __restrict__ ob, const float* __restrict__ x,
               const float* __restrict__ w2, const float* __restrict__ b2,
               const float* __restrict__ scaling, float* __restrict__ out)
{
    const int b = blockIdx.z, n0 = blockIdx.x * 128, ci0 = blockIdx.y * 128;
    const int tid = threadIdx.x;
    const int wave = tid >> 6, lane = tid & 63;
    const int l16 = lane & 15, quad = lane >> 4;
    const int wn = wave & 1, wci = wave >> 1;

    __shared__ __bf16 Zt[128][40];
    __shared__ __bf16 Wt[128][40];

    const __bf16* obb = ob + (size_t)b * CO * NN;

    f32x4 acc[4][4];
    #pragma unroll
    for (int i = 0; i < 4; ++i)
        #pragma unroll
        for (int j = 0; j < 4; ++j) acc[i][j] = f32x4{0,0,0,0};

    const int zn = tid & 127, zc = tid >> 7;

    for (int k0 = 0; k0 < CO; k0 += 32) {
        #pragma unroll
        for (int g = 0; g < 2; ++g) {
            int cg = zc + g * 2;
            v8bf z;
            #pragma unroll
            for (int j = 0; j < 8; ++j)
                z[j] = obb[(size_t)(k0 + cg * 8 + j) * NN + n0 + zn];
            *(v8bf*)&Zt[zn][cg * 8] = z;
        }
        #pragma unroll
        for (int g = 0; g < 4; ++g) {
            int f = tid + 256 * g;
            int ci = f >> 3, cq = f & 7;
            float4 v = *(const float4*)(w2 + (size_t)(ci0 + ci) * CO + k0 + cq * 4);
            *(v4bf*)&Wt[ci][cq * 4] = v4bf{(__bf16)v.x, (__bf16)v.y, (__bf16)v.z, (__bf16)v.w};
        }
        __syncthreads();
        v8bf aw[4], bz[4];
        #pragma unroll
        for (int i = 0; i < 4; ++i) aw[i] = *(const v8bf*)&Wt[wci * 64 + i * 16 + l16][quad * 8];
        #pragma unroll
        for (int j = 0; j < 4; ++j) bz[j] = *(const v8bf*)&Zt[wn * 64 + j * 16 + l16][quad * 8];
        #pragma unroll
        for (int i = 0; i < 4; ++i)
            #pragma unroll
            for (int j = 0; j < 4; ++j)
                acc[i][j] = __builtin_amdgcn_mfma_f32_16x16x32_bf16(aw[i], bz[j], acc[i][j], 0, 0, 0);
        __syncthreads();
    }
    float sc = scaling[0];
    #pragma unroll
    for (int i = 0; i < 4; ++i) {
        int ci = ci0 + wci * 64 + i * 16 + quad * 4;
        #pragma unroll
        for (int r = 0; r < 4; ++r) {
            float bvv = b2[ci + r];
            #pragma unroll
            for (int j = 0; j < 4; ++j) {
                int n = n0 + wn * 64 + j * 16 + l16;
                size_t gi = ((size_t)b * CI + ci + r) * NN + n;
                out[gi] = x[gi] + sc * (acc[i][j][r] + bvv);
            }
        }
    }
}

extern "C" void kernel_launch(void* const* d_in, const int* in_sizes, int n_in,
                              void* d_out, int out_size, void* d_ws, size_t ws_size,
                              hipStream_t stream)
{
    (void)in_sizes; (void)n_in; (void)out_size; (void)ws_size;
    const float* x       = (const float*)d_in[0];
    const float* query   = (const float*)d_in[1];
    const float* key_w   = (const float*)d_in[2];
    const float* key_b   = (const float*)d_in[3];
    const float* val_w   = (const float*)d_in[4];
    const float* val_b   = (const float*)d_in[5];
    const float* query_w = (const float*)d_in[6];
    const float* query_b = (const float*)d_in[7];
    const float* up_w    = (const float*)d_in[8];
    const float* up_b    = (const float*)d_in[9];
    const float* scaling = (const float*)d_in[10];
    float* out = (float*)d_out;

    const size_t TEN = (size_t)NB * NN * CO;   // 4,194,304 elements
    u8* kT  = (u8*)d_ws;                       // [B,N,Co] fp8 (key proj = attn Q)
    u8* qT  = kT + TEN;                        // [B,N,Co] fp8 (query proj = attn K)
    u8* vT2 = qT + TEN;                        // [B,Co,N] fp8
    __bf16* ob    = (__bf16*)(vT2 + TEN);      // [B,N,Co] bf16
    __bf16* Opart = ob + TEN;                  // [SPLIT,B,N,Co] bf16
    float*  lbuf  = (float*)(Opart + (size_t)SPLIT * TEN);  // [SPLIT,B,N]

    dim3 blk(256);
    proj3_kernel<<<dim3(NN / 128, CO / 64, NB), blk, 0, stream>>>(
        x, query, key_w, key_b, val_w, val_b, query_w, query_b, kT, vT2, qT);
    attn_kernel<<<dim3(NN / 128, SPLIT, NB), blk, 0, stream>>>(kT, qT, vT2, Opart, lbuf);
    merge_kernel<<<dim3((NB * NN * CO / 8) / 256), blk, 0, stream>>>(Opart, lbuf, ob);
    up_kernel<<<dim3(NN / 128, CI / 128, NB), blk, 0, stream>>>(ob, x, up_w, up_b, scaling, out);
}

// Round 5
// 206.848 us; speedup vs baseline: 1.1085x; 1.0497x over previous
//
#include <hip/hip_runtime.h>
#include <hip/hip_fp8.h>
#include <math.h>

#define NB 8
#define CI 512
#define CO 256
#define NN 2048           // T*H*W
#define SCALE 0.0625f     // 1/sqrt(CO), applied inside exp in attention
#define SPLIT 4           // KV split factor

typedef __bf16 v8bf __attribute__((ext_vector_type(8)));
typedef __bf16 v4bf __attribute__((ext_vector_type(4)));
typedef float  f32x4  __attribute__((ext_vector_type(4)));
typedef float  f32x16 __attribute__((ext_vector_type(16)));
typedef unsigned char u8;
typedef long i64t;

static __device__ __forceinline__ u8 to_fp8(float x) {
    __hip_fp8_e4m3 t(x);           // OCP e4m3fn on gfx950
    return (u8)t.__x;
}

static __device__ __forceinline__ i64t pack64(unsigned lo, unsigned hi) {
    return (i64t)(((unsigned long long)hi << 32) | (unsigned long long)lo);
}

// ---------------------------------------------------------------------------
// Fused projections (round-1 proven structure, 43.6 us): k = key_w@x
// (fp8 [B,N,Co]), v = val_w@x (fp8 [B,Co,N]), q = query_w@query (fp8 [B,N,Co]).
// Tile 128n x 64co, K-chunk 32, bf16 MFMA. Direct load->cvt->LDS staging
// (explicit reg-prefetch measured SLOWER on this 2-barrier loop: r4 56.6 us).
// ---------------------------------------------------------------------------
__global__ __launch_bounds__(256, 2)
void proj3_kernel(const float* __restrict__ x, const float* __restrict__ query,
                  const float* __restrict__ wk, const float* __restrict__ bk,
                  const float* __restrict__ wv, const float* __restrict__ bv,
                  const float* __restrict__ wq, const float* __restrict__ bq,
                  u8* __restrict__ outK, u8* __restrict__ outV, u8* __restrict__ outQ)
{
    const int b = blockIdx.z, n0 = blockIdx.x * 128, co0 = blockIdx.y * 64;
    const int tid = threadIdx.x;
    const int wave = tid >> 6, lane = tid & 63;
    const int l16 = lane & 15, quad = lane >> 4;
    const int wn = wave & 1, wc = wave >> 1;

    __shared__ __bf16 Xt[128][40];
    __shared__ __bf16 Qt[128][40];
    __shared__ __bf16 Wks[64][40];
    __shared__ __bf16 Wvs[64][40];
    __shared__ __bf16 Wqs[64][40];

    const float* xb = x + (size_t)b * CI * NN;
    const float* qb = query + (size_t)b * CI * NN;

    f32x4 acck[4][2], accv[2][4], accq[4][2];
    #pragma unroll
    for (int i = 0; i < 4; ++i)
        #pragma unroll
        for (int j = 0; j < 2; ++j) {
            acck[i][j] = f32x4{0,0,0,0}; accv[j][i] = f32x4{0,0,0,0};
            accq[i][j] = f32x4{0,0,0,0};
        }

    const int xn = tid & 127;
    const int xc = tid >> 7;

    for (int k0 = 0; k0 < CI; k0 += 32) {
        #pragma unroll
        for (int g = 0; g < 2; ++g) {
            int cg = xc + g * 2;
            v8bf z, w;
            #pragma unroll
            for (int j = 0; j < 8; ++j) {
                z[j] = (__bf16)xb[(size_t)(k0 + cg * 8 + j) * NN + n0 + xn];
                w[j] = (__bf16)qb[(size_t)(k0 + cg * 8 + j) * NN + n0 + xn];
            }
            *(v8bf*)&Xt[xn][cg * 8] = z;
            *(v8bf*)&Qt[xn][cg * 8] = w;
        }
        #pragma unroll
        for (int g = 0; g < 2; ++g) {
            int f = tid + 256 * g;
            int co = f >> 3, cq = f & 7;
            float4 a = *(const float4*)(wk + (size_t)(co0 + co) * CI + k0 + cq * 4);
            float4 c = *(const float4*)(wv + (size_t)(co0 + co) * CI + k0 + cq * 4);
            float4 d = *(const float4*)(wq + (size_t)(co0 + co) * CI + k0 + cq * 4);
            *(v4bf*)&Wks[co][cq * 4] = v4bf{(__bf16)a.x, (__bf16)a.y, (__bf16)a.z, (__bf16)a.w};
            *(v4bf*)&Wvs[co][cq * 4] = v4bf{(__bf16)c.x, (__bf16)c.y, (__bf16)c.z, (__bf16)c.w};
            *(v4bf*)&Wqs[co][cq * 4] = v4bf{(__bf16)d.x, (__bf16)d.y, (__bf16)d.z, (__bf16)d.w};
        }
        __syncthreads();
        v8bf ax[4], aqx[4], bkf[2], bqf[2];
        #pragma unroll
        for (int i = 0; i < 4; ++i) {
            ax[i]  = *(const v8bf*)&Xt[wn * 64 + i * 16 + l16][quad * 8];
            aqx[i] = *(const v8bf*)&Qt[wn * 64 + i * 16 + l16][quad * 8];
        }
        #pragma unroll
        for (int j = 0; j < 2; ++j) {
            bkf[j] = *(const v8bf*)&Wks[wc * 32 + j * 16 + l16][quad * 8];
            bqf[j] = *(const v8bf*)&Wqs[wc * 32 + j * 16 + l16][quad * 8];
        }
        #pragma unroll
        for (int i = 0; i < 4; ++i)
            #pragma unroll
            for (int j = 0; j < 2; ++j) {
                acck[i][j] = __builtin_amdgcn_mfma_f32_16x16x32_bf16(ax[i],  bkf[j], acck[i][j], 0, 0, 0);
                accq[i][j] = __builtin_amdgcn_mfma_f32_16x16x32_bf16(aqx[i], bqf[j], accq[i][j], 0, 0, 0);
            }
        {
            v8bf avf[2];
            #pragma unroll
            for (int j = 0; j < 2; ++j) avf[j] = *(const v8bf*)&Wvs[wc * 32 + j * 16 + l16][quad * 8];
            #pragma unroll
            for (int j = 0; j < 2; ++j)
                #pragma unroll
                for (int i = 0; i < 4; ++i)
                    accv[j][i] = __builtin_amdgcn_mfma_f32_16x16x32_bf16(avf[j], ax[i], accv[j][i], 0, 0, 0);
        }
        __syncthreads();
    }
    // k and q epilogues: D[m=n][col=co], fp8 out
    #pragma unroll
    for (int i = 0; i < 4; ++i) {
        int n = n0 + wn * 64 + i * 16 + quad * 4;
        #pragma unroll
        for (int j = 0; j < 2; ++j) {
            int co = co0 + wc * 32 + j * 16 + l16;
            float bkk = bk[co], bqq = bq[co];
            u8* dk = outK + ((size_t)b * NN + n) * CO + co;
            u8* dq = outQ + ((size_t)b * NN + n) * CO + co;
            #pragma unroll
            for (int r = 0; r < 4; ++r) {
                dk[(size_t)r * CO] = to_fp8(acck[i][j][r] + bkk);
                dq[(size_t)r * CO] = to_fp8(accq[i][j][r] + bqq);
            }
        }
    }
    // v epilogue: D[m=co][col=n]
    #pragma unroll
    for (int j = 0; j < 2; ++j) {
        int co = co0 + wc * 32 + j * 16 + quad * 4;
        #pragma unroll
        for (int r = 0; r < 4; ++r) {
            float bvv = bv[co + r];
            #pragma unroll
            for (int i = 0; i < 4; ++i) {
                int n = n0 + wn * 64 + i * 16 + l16;
                outV[((size_t)b * CO + co + r) * NN + n] = to_fp8(accv[j][i][r] + bvv);
            }
        }
    }
}

// ---------------------------------------------------------------------------
// Flash attention v2: swapped-operand QK^T (D[kv][q]) keeps each lane's full
// P row in registers -> in-register fp8 pack (cvt_pk_fp8) feeds PV's A-frag
// DIRECTLY (k-slot permutation absorbed into the V LDS dword order at staging:
// middle-dword swap). No duplicated QK^T, no P LDS round-trip, no cross-lane.
// Each wave: 32 q-rows x full Co=256 (acc 8x f32x16 = 128 VGPR). Block = 128q,
// 4 waves. LDS qword-padded: Ks pitch 264B / Vt pitch 72B -> 2-way max (free).
// T14 async stage split (issue global loads under compute), T5 setprio.
// ---------------------------------------------------------------------------
__global__ __launch_bounds__(256, 2)
void attn_kernel(const u8* __restrict__ kT, const u8* __restrict__ qT,
                 const u8* __restrict__ vT2, __bf16* __restrict__ Opart,
                 float* __restrict__ lbuf)
{
    const int b = blockIdx.z, part = blockIdx.y, n0 = blockIdx.x * 128;
    const int tid = threadIdx.x;
    const int wave = tid >> 6, lane = tid & 63;
    const int l32 = lane & 31, hs = lane >> 5;

    __shared__ i64t Ks8[64][33];    // [kv][c qwords], pitch 264 B (66 dw: 2-way)
    __shared__ i64t Vt8[256][9];    // [co][kv qwords, dword-interleaved], 72 B

    const int start = part * (NN / SPLIT);        // 512 kv per part
    const u8* Ksrc = qT + ((size_t)b * NN + start) * CO;   // attn-K rows [kv][c]
    const u8* Vsrc = vT2 + (size_t)b * CO * NN + start;    // [co][kv]

    // resident Q fragments (B operand): lane holds Q[q=l32][c=s*16+hs*8 ..+7]
    i64t aq[16];
    {
        const u8* qrow = kT + ((size_t)b * NN + n0 + wave * 32 + l32) * CO + hs * 8;
        #pragma unroll
        for (int s = 0; s < 16; ++s) aq[s] = *(const i64t*)(qrow + s * 16);
    }

    f32x16 acc[8];
    #pragma unroll
    for (int t = 0; t < 8; ++t)
        #pragma unroll
        for (int r = 0; r < 16; ++r) acc[t][r] = 0.f;
    float lp = 0.f;

    // T14: stage tile 0 into registers
    int4 kx[4], vx[4];
    #pragma unroll
    for (int r2 = 0; r2 < 4; ++r2) {
        int c = tid + 256 * r2;
        kx[r2] = *(const int4*)(Ksrc + (size_t)(c >> 4) * CO + (c & 15) * 16);
        vx[r2] = *(const int4*)(Vsrc + (size_t)(c >> 2) * NN + (c & 3) * 16);
    }

    for (int it = 0; it < NN / SPLIT / 64; ++it) {
        // registers -> LDS (split b64 writes; V gets middle-dword swap so that
        // row qword 2g   = kv{16g+0..3, 16g+8..11}  (PV slots 0-7,  hs=0)
        //     qword 2g+1 = kv{16g+4..7, 16g+12..15} (PV slots 8-15, hs=1)
        #pragma unroll
        for (int r2 = 0; r2 < 4; ++r2) {
            int c = tid + 256 * r2;
            i64t* kd = &Ks8[c >> 4][(c & 15) * 2];
            kd[0] = *(const i64t*)&kx[r2].x;
            kd[1] = *(const i64t*)&kx[r2].z;
            i64t* vd = &Vt8[c >> 2][(c & 3) * 2];
            vd[0] = pack64((unsigned)vx[r2].x, (unsigned)vx[r2].z);
            vd[1] = pack64((unsigned)vx[r2].y, (unsigned)vx[r2].w);
        }
        __syncthreads();

        // issue next tile's global loads; latency hides under QK^T + PV
        if (it + 1 < NN / SPLIT / 64) {
            const u8* Kit = Ksrc + (size_t)(it + 1) * 64 * CO;
            const u8* Vit = Vsrc + (it + 1) * 64;
            #pragma unroll
            for (int r2 = 0; r2 < 4; ++r2) {
                int c = tid + 256 * r2;
                kx[r2] = *(const int4*)(Kit + (size_t)(c >> 4) * CO + (c & 15) * 16);
                vx[r2] = *(const int4*)(Vit + (size_t)(c >> 2) * NN + (c & 3) * 16);
            }
        }

        // S^T = K Q^T per 32-kv subtile: D[kv][q=l32]; softmax lane-local
        int dpk[8];
        #pragma unroll
        for (int sub = 0; sub < 2; ++sub) {
            f32x16 sacc;
            #pragma unroll
            for (int r = 0; r < 16; ++r) sacc[r] = 0.f;
            __builtin_amdgcn_s_setprio(1);
            #pragma unroll
            for (int s = 0; s < 16; ++s) {
                i64t kf = Ks8[sub * 32 + l32][s * 2 + hs];
                sacc = __builtin_amdgcn_mfma_f32_32x32x16_fp8_fp8(kf, aq[s], sacc, 0, 0, 0);
            }
            __builtin_amdgcn_s_setprio(0);
            // stats-free softmax: p = exp(S/16); reg r -> kv = (r&3)+8*(r>>2)+4*hs
            #pragma unroll
            for (int r = 0; r < 16; ++r) {
                sacc[r] = __expf(sacc[r] * SCALE);
                lp += sacc[r];
            }
            #pragma unroll
            for (int g = 0; g < 4; ++g) {
                int lo = __builtin_amdgcn_cvt_pk_fp8_f32(sacc[4*g+0], sacc[4*g+1], 0, false);
                dpk[sub * 4 + g] = __builtin_amdgcn_cvt_pk_fp8_f32(sacc[4*g+2], sacc[4*g+3], lo, true);
            }
        }
        // PV A-frags: chunk c (16 kv) = {dpk[2c], dpk[2c+1]} — already slot-ordered
        i64t pa[4];
        #pragma unroll
        for (int c = 0; c < 4; ++c)
            pa[c] = pack64((unsigned)dpk[2 * c], (unsigned)dpk[2 * c + 1]);

        __builtin_amdgcn_s_setprio(1);
        #pragma unroll
        for (int t = 0; t < 8; ++t) {
            #pragma unroll
            for (int c = 0; c < 4; ++c) {
                i64t bvf = Vt8[t * 32 + l32][c * 2 + hs];
                acc[t] = __builtin_amdgcn_mfma_f32_32x32x16_fp8_fp8(pa[c], bvf, acc[t], 0, 0, 0);
            }
        }
        __builtin_amdgcn_s_setprio(0);
        __syncthreads();   // LDS reads done before next tile's writes
    }

    // row sums: lane holds half of q-row l32's kv mass; partner is lane^32
    lp += __shfl_xor(lp, 32);
    if (hs == 0)
        lbuf[(size_t)(part * NB + b) * NN + n0 + wave * 32 + l32] = lp;

    // store unnormalized bf16 partial: D[q over regs][co = t*32 + l32]
    const size_t qbase = (size_t)(part * NB + b) * NN + n0 + wave * 32;
    #pragma unroll
    for (int t = 0; t < 8; ++t)
        #pragma unroll
        for (int r = 0; r < 16; ++r) {
            int row = (r & 3) + 8 * (r >> 2) + 4 * hs;
            Opart[(qbase + row) * CO + t * 32 + l32] = (__bf16)acc[t][r];
        }
}

// ---------------------------------------------------------------------------
// Merge SPLIT partials: O = (sum O_i) / (sum l_i) -> ob bf16 [B,N,Co]
// ---------------------------------------------------------------------------
__global__ __launch_bounds__(256)
void merge_kernel(const __bf16* __restrict__ Opart, const float* __restrict__ lbuf,
                  __bf16* __restrict__ ob)
{
    int gid = blockIdx.x * 256 + threadIdx.x;
    int chunk = gid & 31;
    int row = gid >> 5;        // b*NN + n
    float ls = 0.f;
    #pragma unroll
    for (int p = 0; p < SPLIT; ++p) ls += lbuf[(size_t)p * NB * NN + row];
    float inv = 1.0f / ls;
    float o[8] = {0,0,0,0,0,0,0,0};
    #pragma unroll
    for (int p = 0; p < SPLIT; ++p) {
        v8bf v = *(const v8bf*)(Opart + ((size_t)p * NB * NN + row) * CO + chunk * 8);
        #pragma unroll
        for (int j = 0; j < 8; ++j) o[j] += (float)v[j];
    }
    v8bf res;
    #pragma unroll
    for (int j = 0; j < 8; ++j) res[j] = (__bf16)(o[j] * inv);
    *(v8bf*)(ob + (size_t)row * CO + chunk * 8) = res;
}

// ---------------------------------------------------------------------------
// up v2: out[b][ci][n] = x + sc*(b2[ci] + sum_cv w2[ci][cv] * Z'[cv][n]),
// Z'[cv][n] = ob_flat[b][cv*NN + n] (raw-reshape view, contiguous along n).
// Staging fix (Common-mistake #2): Z loaded as v8bf ALONG n (16 vec loads vs
// 128 scalar u16 loads per thread). Transposed LDS write (8 rows x 1 col per
// thread) uses XOR-swizzled column col = cv ^ (8*((row>>3)&3)) — thread-
// constant on write (thread owns one 8-row stripe), b128-aligned on read.
// ---------------------------------------------------------------------------
__global__ __launch_bounds__(256)
void up_kernel(const __bf16* __restrict__ ob, const float* __restrict__ x,
               const float* __restrict__ w2, const float* __restrict__ b2,
               const float* __restrict__ scaling, float* __restrict__ out)
{
    const int b = blockIdx.z, n0 = blockIdx.x * 128, ci0 = blockIdx.y * 128;
    const int tid = threadIdx.x;
    const int wave = tid >> 6, lane = tid & 63;
    const int l16 = lane & 15, quad = lane >> 4;
    const int wn = wave & 1, wci = wave >> 1;

    __shared__ __bf16 Zt[128][40];
    __shared__ __bf16 Wt[128][40];

    const __bf16* obb = ob + (size_t)b * CO * NN;

    f32x4 acc[4][4];
    #pragma unroll
    for (int i = 0; i < 4; ++i)
        #pragma unroll
        for (int j = 0; j < 4; ++j) acc[i][j] = f32x4{0,0,0,0};

    // Z staging coords: thread owns 8 consecutive n (one row-stripe) x 1 cv,
    // two units (cv and cv+16). m = stripe index = row>>3, thread-constant.
    const int zm = tid & 15;          // n-stripe: rows zm*8 .. zm*8+7
    const int zcv = tid >> 4;         // cv lane 0..15
    const int zsw = 8 * (zm & 3);     // XOR column swizzle (thread-constant)

    for (int k0 = 0; k0 < CO; k0 += 32) {
        #pragma unroll
        for (int u = 0; u < 2; ++u) {
            const int cv = zcv + 16 * u;
            v8bf z = *(const v8bf*)(obb + (size_t)(k0 + cv) * NN + n0 + zm * 8);
            const int col = cv ^ zsw;
            #pragma unroll
            for (int i = 0; i < 8; ++i)
                Zt[zm * 8 + i][col] = z[i];
        }
        #pragma unroll
        for (int g = 0; g < 4; ++g) {
            int f = tid + 256 * g;
            int ci = f >> 3, cq = f & 7;
            float4 v = *(const float4*)(w2 + (size_t)(ci0 + ci) * CO + k0 + cq * 4);
            *(v4bf*)&Wt[ci][cq * 4] = v4bf{(__bf16)v.x, (__bf16)v.y, (__bf16)v.z, (__bf16)v.w};
        }
        __syncthreads();
        v8bf aw[4], bz[4];
        #pragma unroll
        for (int i = 0; i < 4; ++i) aw[i] = *(const v8bf*)&Wt[wci * 64 + i * 16 + l16][quad * 8];
        #pragma unroll
        for (int j = 0; j < 4; ++j) {
            const int row = wn * 64 + j * 16 + l16;
            const int col = (quad ^ ((row >> 3) & 3)) * 8;   // inverse swizzle
            bz[j] = *(const v8bf*)&Zt[row][col];
        }
        #pragma unroll
        for (int i = 0; i < 4; ++i)
            #pragma unroll
            for (int j = 0; j < 4; ++j)
                acc[i][j] = __builtin_amdgcn_mfma_f32_16x16x32_bf16(aw[i], bz[j], acc[i][j], 0, 0, 0);
        __syncthreads();
    }
    float sc = scaling[0];
    #pragma unroll
    for (int i = 0; i < 4; ++i) {
        int ci = ci0 + wci * 64 + i * 16 + quad * 4;
        #pragma unroll
        for (int r = 0; r < 4; ++r) {
            float bvv = b2[ci + r];
            #pragma unroll
            for (int j = 0; j < 4; ++j) {
                int n = n0 + wn * 64 + j * 16 + l16;
                size_t gi = ((size_t)b * CI + ci + r) * NN + n;
                out[gi] = x[gi] + sc * (acc[i][j][r] + bvv);
            }
        }
    }
}

extern "C" void kernel_launch(void* const* d_in, const int* in_sizes, int n_in,
                              void* d_out, int out_size, void* d_ws, size_t ws_size,
                              hipStream_t stream)
{
    (void)in_sizes; (void)n_in; (void)out_size; (void)ws_size;
    const float* x       = (const float*)d_in[0];
    const float* query   = (const float*)d_in[1];
    const float* key_w   = (const float*)d_in[2];
    const float* key_b   = (const float*)d_in[3];
    const float* val_w   = (const float*)d_in[4];
    const float* val_b   = (const float*)d_in[5];
    const float* query_w = (const float*)d_in[6];
    const float* query_b = (const float*)d_in[7];
    const float* up_w    = (const float*)d_in[8];
    const float* up_b    = (const float*)d_in[9];
    const float* scaling = (const float*)d_in[10];
    float* out = (float*)d_out;

    const size_t TEN = (size_t)NB * NN * CO;   // 4,194,304 elements
    u8* kT  = (u8*)d_ws;                       // [B,N,Co] fp8 (key proj = attn Q)
    u8* qT  = kT + TEN;                        // [B,N,Co] fp8 (query proj = attn K)
    u8* vT2 = qT + TEN;                        // [B,Co,N] fp8
    __bf16* ob    = (__bf16*)(vT2 + TEN);      // [B,N,Co] bf16
    __bf16* Opart = ob + TEN;                  // [SPLIT,B,N,Co] bf16
    float*  lbuf  = (float*)(Opart + (size_t)SPLIT * TEN);  // [SPLIT,B,N]

    dim3 blk(256);
    proj3_kernel<<<dim3(NN / 128, CO / 64, NB), blk, 0, stream>>>(
        x, query, key_w, key_b, val_w, val_b, query_w, query_b, kT, vT2, qT);
    attn_kernel<<<dim3(NN / 128, SPLIT, NB), blk, 0, stream>>>(kT, qT, vT2, Opart, lbuf);
    merge_kernel<<<dim3((NB * NN * CO / 8) / 256), blk, 0, stream>>>(Opart, lbuf, ob);
    up_kernel<<<dim3(NN / 128, CI / 128, NB), blk, 0, stream>>>(ob, x, up_w, up_b, scaling, out);
}

// Round 6
// 205.789 us; speedup vs baseline: 1.1142x; 1.0051x over previous
//
#include <hip/hip_runtime.h>
#include <hip/hip_fp8.h>
#include <math.h>

#define NB 8
#define CI 512
#define CO 256
#define NN 2048           // T*H*W
#define SCALE 0.0625f     // 1/sqrt(CO), applied inside exp in attention
#define SPLIT 4           // KV split factor

typedef __bf16 v8bf __attribute__((ext_vector_type(8)));
typedef __bf16 v4bf __attribute__((ext_vector_type(4)));
typedef float  f32x4  __attribute__((ext_vector_type(4)));
typedef float  f32x16 __attribute__((ext_vector_type(16)));
typedef unsigned char u8;
typedef long i64t;

static __device__ __forceinline__ u8 to_fp8(float x) {
    __hip_fp8_e4m3 t(x);           // OCP e4m3fn on gfx950
    return (u8)t.__x;
}

static __device__ __forceinline__ i64t pack64(unsigned lo, unsigned hi) {
    return (i64t)(((unsigned long long)hi << 32) | (unsigned long long)lo);
}

// ---------------------------------------------------------------------------
// Fused projections (round-1 proven structure, 43.6 us): k = key_w@x
// (fp8 [B,N,Co]), v = val_w@x (fp8 [B,Co,N]), q = query_w@query (fp8 [B,N,Co]).
// Tile 128n x 64co, K-chunk 32, bf16 MFMA. Direct load->cvt->LDS staging
// (explicit reg-prefetch measured SLOWER on this 2-barrier loop: r4 56.6 us;
// 64x64 tile also slower: r3 67.4 us. Do not perturb without new evidence.)
// ---------------------------------------------------------------------------
__global__ __launch_bounds__(256, 2)
void proj3_kernel(const float* __restrict__ x, const float* __restrict__ query,
                  const float* __restrict__ wk, const float* __restrict__ bk,
                  const float* __restrict__ wv, const float* __restrict__ bv,
                  const float* __restrict__ wq, const float* __restrict__ bq,
                  u8* __restrict__ outK, u8* __restrict__ outV, u8* __restrict__ outQ)
{
    const int b = blockIdx.z, n0 = blockIdx.x * 128, co0 = blockIdx.y * 64;
    const int tid = threadIdx.x;
    const int wave = tid >> 6, lane = tid & 63;
    const int l16 = lane & 15, quad = lane >> 4;
    const int wn = wave & 1, wc = wave >> 1;

    __shared__ __bf16 Xt[128][40];
    __shared__ __bf16 Qt[128][40];
    __shared__ __bf16 Wks[64][40];
    __shared__ __bf16 Wvs[64][40];
    __shared__ __bf16 Wqs[64][40];

    const float* xb = x + (size_t)b * CI * NN;
    const float* qb = query + (size_t)b * CI * NN;

    f32x4 acck[4][2], accv[2][4], accq[4][2];
    #pragma unroll
    for (int i = 0; i < 4; ++i)
        #pragma unroll
        for (int j = 0; j < 2; ++j) {
            acck[i][j] = f32x4{0,0,0,0}; accv[j][i] = f32x4{0,0,0,0};
            accq[i][j] = f32x4{0,0,0,0};
        }

    const int xn = tid & 127;
    const int xc = tid >> 7;

    for (int k0 = 0; k0 < CI; k0 += 32) {
        #pragma unroll
        for (int g = 0; g < 2; ++g) {
            int cg = xc + g * 2;
            v8bf z, w;
            #pragma unroll
            for (int j = 0; j < 8; ++j) {
                z[j] = (__bf16)xb[(size_t)(k0 + cg * 8 + j) * NN + n0 + xn];
                w[j] = (__bf16)qb[(size_t)(k0 + cg * 8 + j) * NN + n0 + xn];
            }
            *(v8bf*)&Xt[xn][cg * 8] = z;
            *(v8bf*)&Qt[xn][cg * 8] = w;
        }
        #pragma unroll
        for (int g = 0; g < 2; ++g) {
            int f = tid + 256 * g;
            int co = f >> 3, cq = f & 7;
            float4 a = *(const float4*)(wk + (size_t)(co0 + co) * CI + k0 + cq * 4);
            float4 c = *(const float4*)(wv + (size_t)(co0 + co) * CI + k0 + cq * 4);
            float4 d = *(const float4*)(wq + (size_t)(co0 + co) * CI + k0 + cq * 4);
            *(v4bf*)&Wks[co][cq * 4] = v4bf{(__bf16)a.x, (__bf16)a.y, (__bf16)a.z, (__bf16)a.w};
            *(v4bf*)&Wvs[co][cq * 4] = v4bf{(__bf16)c.x, (__bf16)c.y, (__bf16)c.z, (__bf16)c.w};
            *(v4bf*)&Wqs[co][cq * 4] = v4bf{(__bf16)d.x, (__bf16)d.y, (__bf16)d.z, (__bf16)d.w};
        }
        __syncthreads();
        v8bf ax[4], aqx[4], bkf[2], bqf[2];
        #pragma unroll
        for (int i = 0; i < 4; ++i) {
            ax[i]  = *(const v8bf*)&Xt[wn * 64 + i * 16 + l16][quad * 8];
            aqx[i] = *(const v8bf*)&Qt[wn * 64 + i * 16 + l16][quad * 8];
        }
        #pragma unroll
        for (int j = 0; j < 2; ++j) {
            bkf[j] = *(const v8bf*)&Wks[wc * 32 + j * 16 + l16][quad * 8];
            bqf[j] = *(const v8bf*)&Wqs[wc * 32 + j * 16 + l16][quad * 8];
        }
        #pragma unroll
        for (int i = 0; i < 4; ++i)
            #pragma unroll
            for (int j = 0; j < 2; ++j) {
                acck[i][j] = __builtin_amdgcn_mfma_f32_16x16x32_bf16(ax[i],  bkf[j], acck[i][j], 0, 0, 0);
                accq[i][j] = __builtin_amdgcn_mfma_f32_16x16x32_bf16(aqx[i], bqf[j], accq[i][j], 0, 0, 0);
            }
        {
            v8bf avf[2];
            #pragma unroll
            for (int j = 0; j < 2; ++j) avf[j] = *(const v8bf*)&Wvs[wc * 32 + j * 16 + l16][quad * 8];
            #pragma unroll
            for (int j = 0; j < 2; ++j)
                #pragma unroll
                for (int i = 0; i < 4; ++i)
                    accv[j][i] = __builtin_amdgcn_mfma_f32_16x16x32_bf16(avf[j], ax[i], accv[j][i], 0, 0, 0);
        }
        __syncthreads();
    }
    // k and q epilogues: D[m=n][col=co], fp8 out
    #pragma unroll
    for (int i = 0; i < 4; ++i) {
        int n = n0 + wn * 64 + i * 16 + quad * 4;
        #pragma unroll
        for (int j = 0; j < 2; ++j) {
            int co = co0 + wc * 32 + j * 16 + l16;
            float bkk = bk[co], bqq = bq[co];
            u8* dk = outK + ((size_t)b * NN + n) * CO + co;
            u8* dq = outQ + ((size_t)b * NN + n) * CO + co;
            #pragma unroll
            for (int r = 0; r < 4; ++r) {
                dk[(size_t)r * CO] = to_fp8(acck[i][j][r] + bkk);
                dq[(size_t)r * CO] = to_fp8(accq[i][j][r] + bqq);
            }
        }
    }
    // v epilogue: D[m=co][col=n]
    #pragma unroll
    for (int j = 0; j < 2; ++j) {
        int co = co0 + wc * 32 + j * 16 + quad * 4;
        #pragma unroll
        for (int r = 0; r < 4; ++r) {
            float bvv = bv[co + r];
            #pragma unroll
            for (int i = 0; i < 4; ++i) {
                int n = n0 + wn * 64 + i * 16 + l16;
                outV[((size_t)b * CO + co + r) * NN + n] = to_fp8(accv[j][i][r] + bvv);
            }
        }
    }
}

// ---------------------------------------------------------------------------
// Flash attention v2: swapped-operand QK^T (D[kv][q]) keeps each lane's full
// P row in registers -> in-register fp8 pack (cvt_pk_fp8) feeds PV's A-frag
// DIRECTLY (k-slot permutation absorbed into the V LDS dword order at staging:
// middle-dword swap). No duplicated QK^T, no P LDS round-trip, no cross-lane.
// Each wave: 32 q-rows x full Co=256 (acc 8x f32x16 = 128 VGPR). Block = 128q,
// 4 waves. LDS qword-padded: Ks pitch 264B / Vt pitch 72B -> 2-way max (free).
// T14 async stage split (issue global loads under compute), T5 setprio.
// ---------------------------------------------------------------------------
__global__ __launch_bounds__(256, 2)
void attn_kernel(const u8* __restrict__ kT, const u8* __restrict__ qT,
                 const u8* __restrict__ vT2, __bf16* __restrict__ Opart,
                 float* __restrict__ lbuf)
{
    const int b = blockIdx.z, part = blockIdx.y, n0 = blockIdx.x * 128;
    const int tid = threadIdx.x;
    const int wave = tid >> 6, lane = tid & 63;
    const int l32 = lane & 31, hs = lane >> 5;

    __shared__ i64t Ks8[64][33];    // [kv][c qwords], pitch 264 B (66 dw: 2-way)
    __shared__ i64t Vt8[256][9];    // [co][kv qwords, dword-interleaved], 72 B

    const int start = part * (NN / SPLIT);        // 512 kv per part
    const u8* Ksrc = qT + ((size_t)b * NN + start) * CO;   // attn-K rows [kv][c]
    const u8* Vsrc = vT2 + (size_t)b * CO * NN + start;    // [co][kv]

    // resident Q fragments (B operand): lane holds Q[q=l32][c=s*16+hs*8 ..+7]
    i64t aq[16];
    {
        const u8* qrow = kT + ((size_t)b * NN + n0 + wave * 32 + l32) * CO + hs * 8;
        #pragma unroll
        for (int s = 0; s < 16; ++s) aq[s] = *(const i64t*)(qrow + s * 16);
    }

    f32x16 acc[8];
    #pragma unroll
    for (int t = 0; t < 8; ++t)
        #pragma unroll
        for (int r = 0; r < 16; ++r) acc[t][r] = 0.f;
    float lp = 0.f;

    // T14: stage tile 0 into registers
    int4 kx[4], vx[4];
    #pragma unroll
    for (int r2 = 0; r2 < 4; ++r2) {
        int c = tid + 256 * r2;
        kx[r2] = *(const int4*)(Ksrc + (size_t)(c >> 4) * CO + (c & 15) * 16);
        vx[r2] = *(const int4*)(Vsrc + (size_t)(c >> 2) * NN + (c & 3) * 16);
    }

    for (int it = 0; it < NN / SPLIT / 64; ++it) {
        // registers -> LDS (split b64 writes; V gets middle-dword swap so that
        // row qword 2g   = kv{16g+0..3, 16g+8..11}  (PV slots 0-7,  hs=0)
        //     qword 2g+1 = kv{16g+4..7, 16g+12..15} (PV slots 8-15, hs=1)
        #pragma unroll
        for (int r2 = 0; r2 < 4; ++r2) {
            int c = tid + 256 * r2;
            i64t* kd = &Ks8[c >> 4][(c & 15) * 2];
            kd[0] = *(const i64t*)&kx[r2].x;
            kd[1] = *(const i64t*)&kx[r2].z;
            i64t* vd = &Vt8[c >> 2][(c & 3) * 2];
            vd[0] = pack64((unsigned)vx[r2].x, (unsigned)vx[r2].z);
            vd[1] = pack64((unsigned)vx[r2].y, (unsigned)vx[r2].w);
        }
        __syncthreads();

        // issue next tile's global loads; latency hides under QK^T + PV
        if (it + 1 < NN / SPLIT / 64) {
            const u8* Kit = Ksrc + (size_t)(it + 1) * 64 * CO;
            const u8* Vit = Vsrc + (it + 1) * 64;
            #pragma unroll
            for (int r2 = 0; r2 < 4; ++r2) {
                int c = tid + 256 * r2;
                kx[r2] = *(const int4*)(Kit + (size_t)(c >> 4) * CO + (c & 15) * 16);
                vx[r2] = *(const int4*)(Vit + (size_t)(c >> 2) * NN + (c & 3) * 16);
            }
        }

        // S^T = K Q^T per 32-kv subtile: D[kv][q=l32]; softmax lane-local
        int dpk[8];
        #pragma unroll
        for (int sub = 0; sub < 2; ++sub) {
            f32x16 sacc;
            #pragma unroll
            for (int r = 0; r < 16; ++r) sacc[r] = 0.f;
            __builtin_amdgcn_s_setprio(1);
            #pragma unroll
            for (int s = 0; s < 16; ++s) {
                i64t kf = Ks8[sub * 32 + l32][s * 2 + hs];
                sacc = __builtin_amdgcn_mfma_f32_32x32x16_fp8_fp8(kf, aq[s], sacc, 0, 0, 0);
            }
            __builtin_amdgcn_s_setprio(0);
            // stats-free softmax: p = exp(S/16); reg r -> kv = (r&3)+8*(r>>2)+4*hs
            #pragma unroll
            for (int r = 0; r < 16; ++r) {
                sacc[r] = __expf(sacc[r] * SCALE);
                lp += sacc[r];
            }
            #pragma unroll
            for (int g = 0; g < 4; ++g) {
                int lo = __builtin_amdgcn_cvt_pk_fp8_f32(sacc[4*g+0], sacc[4*g+1], 0, false);
                dpk[sub * 4 + g] = __builtin_amdgcn_cvt_pk_fp8_f32(sacc[4*g+2], sacc[4*g+3], lo, true);
            }
        }
        // PV A-frags: chunk c (16 kv) = {dpk[2c], dpk[2c+1]} — already slot-ordered
        i64t pa[4];
        #pragma unroll
        for (int c = 0; c < 4; ++c)
            pa[c] = pack64((unsigned)dpk[2 * c], (unsigned)dpk[2 * c + 1]);

        __builtin_amdgcn_s_setprio(1);
        #pragma unroll
        for (int t = 0; t < 8; ++t) {
            #pragma unroll
            for (int c = 0; c < 4; ++c) {
                i64t bvf = Vt8[t * 32 + l32][c * 2 + hs];
                acc[t] = __builtin_amdgcn_mfma_f32_32x32x16_fp8_fp8(pa[c], bvf, acc[t], 0, 0, 0);
            }
        }
        __builtin_amdgcn_s_setprio(0);
        __syncthreads();   // LDS reads done before next tile's writes
    }

    // row sums: lane holds half of q-row l32's kv mass; partner is lane^32
    lp += __shfl_xor(lp, 32);
    if (hs == 0)
        lbuf[(size_t)(part * NB + b) * NN + n0 + wave * 32 + l32] = lp;

    // store unnormalized bf16 partial: D[q over regs][co = t*32 + l32]
    const size_t qbase = (size_t)(part * NB + b) * NN + n0 + wave * 32;
    #pragma unroll
    for (int t = 0; t < 8; ++t)
        #pragma unroll
        for (int r = 0; r < 16; ++r) {
            int row = (r & 3) + 8 * (r >> 2) + 4 * hs;
            Opart[(qbase + row) * CO + t * 32 + l32] = (__bf16)acc[t][r];
        }
}

// ---------------------------------------------------------------------------
// up v3: merge fused into staging. out[b][ci][n] = x + sc*(b2[ci] +
// sum_cv w2[ci][cv] * Z'[cv][n]) where Z'[cv][n] = (sum_p Opart_p)/(sum_p l_p)
// viewed through the raw [B,N,Co]->[B,Co,N] reshape. For a fixed block the
// softmax row n_orig = cv*8 + (n0>>8) (constant across each 8-elem run and
// across the 128-n tile), so a 256-entry LDS invl table indexed by cv covers
// all chunks. Eliminates merge_kernel (40 MB pass + launch) and the ob buffer;
// arithmetic identical minus one bf16 round-trip.
// ---------------------------------------------------------------------------
__global__ __launch_bounds__(256)
void up_kernel(const __bf16* __restrict__ Opart, const float* __restrict__ lbuf,
               const float* __restrict__ x,
               const float* __restrict__ w2, const float* __restrict__ b2,
               const float* __restrict__ scaling, float* __restrict__ out)
{
    const int b = blockIdx.z, n0 = blockIdx.x * 128, ci0 = blockIdx.y * 128;
    const int tid = threadIdx.x;
    const int wave = tid >> 6, lane = tid & 63;
    const int l16 = lane & 15, quad = lane >> 4;
    const int wn = wave & 1, wci = wave >> 1;

    __shared__ __bf16 Zt[128][40];
    __shared__ __bf16 Wt[128][40];
    __shared__ float invl[256];

    const size_t PSTRIDE = (size_t)NB * NN * CO;            // Opart part stride
    const __bf16* Opb = Opart + (size_t)b * NN * CO;        // this batch, part 0

    // per-block denominator table: invl[cv] = 1 / sum_p l_p[cv*8 + (n0>>8)]
    {
        const int norig = tid * 8 + (n0 >> 8);
        float ls = 0.f;
        #pragma unroll
        for (int p = 0; p < SPLIT; ++p)
            ls += lbuf[(size_t)(p * NB + b) * NN + norig];
        invl[tid] = 1.0f / ls;
    }
    __syncthreads();

    f32x4 acc[4][4];
    #pragma unroll
    for (int i = 0; i < 4; ++i)
        #pragma unroll
        for (int j = 0; j < 4; ++j) acc[i][j] = f32x4{0,0,0,0};

    // Z staging coords: thread owns 8 consecutive n (one row-stripe) x 1 cv,
    // two units (cv and cv+16). Stripe zm = row>>3, thread-constant.
    const int zm = tid & 15;          // n-stripe: rows zm*8 .. zm*8+7
    const int zcv = tid >> 4;         // cv lane 0..15
    const int zsw = 8 * (zm & 3);     // XOR column swizzle (thread-constant)

    for (int k0 = 0; k0 < CO; k0 += 32) {
        #pragma unroll
        for (int u = 0; u < 2; ++u) {
            const int cv = zcv + 16 * u;
            const size_t fbase = (size_t)(k0 + cv) * NN + n0 + zm * 8;
            float s[8] = {0,0,0,0,0,0,0,0};
            #pragma unroll
            for (int p = 0; p < SPLIT; ++p) {
                v8bf v = *(const v8bf*)(Opb + (size_t)p * PSTRIDE + fbase);
                #pragma unroll
                for (int j = 0; j < 8; ++j) s[j] += (float)v[j];
            }
            const float il = invl[k0 + cv];
            const int col = cv ^ zsw;
            #pragma unroll
            for (int i = 0; i < 8; ++i)
                Zt[zm * 8 + i][col] = (__bf16)(s[i] * il);
        }
        #pragma unroll
        for (int g = 0; g < 4; ++g) {
            int f = tid + 256 * g;
            int ci = f >> 3, cq = f & 7;
            float4 v = *(const float4*)(w2 + (size_t)(ci0 + ci) * CO + k0 + cq * 4);
            *(v4bf*)&Wt[ci][cq * 4] = v4bf{(__bf16)v.x, (__bf16)v.y, (__bf16)v.z, (__bf16)v.w};
        }
        __syncthreads();
        v8bf aw[4], bz[4];
        #pragma unroll
        for (int i = 0; i < 4; ++i) aw[i] = *(const v8bf*)&Wt[wci * 64 + i * 16 + l16][quad * 8];
        #pragma unroll
        for (int j = 0; j < 4; ++j) {
            const int row = wn * 64 + j * 16 + l16;
            const int col = (quad ^ ((row >> 3) & 3)) * 8;   // inverse swizzle
            bz[j] = *(const v8bf*)&Zt[row][col];
        }
        #pragma unroll
        for (int i = 0; i < 4; ++i)
            #pragma unroll
            for (int j = 0; j < 4; ++j)
                acc[i][j] = __builtin_amdgcn_mfma_f32_16x16x32_bf16(aw[i], bz[j], acc[i][j], 0, 0, 0);
        __syncthreads();
    }
    float sc = scaling[0];
    #pragma unroll
    for (int i = 0; i < 4; ++i) {
        int ci = ci0 + wci * 64 + i * 16 + quad * 4;
        #pragma unroll
        for (int r = 0; r < 4; ++r) {
            float bvv = b2[ci + r];
            #pragma unroll
            for (int j = 0; j < 4; ++j) {
                int n = n0 + wn * 64 + j * 16 + l16;
                size_t gi = ((size_t)b * CI + ci + r) * NN + n;
                out[gi] = x[gi] + sc * (acc[i][j][r] + bvv);
            }
        }
    }
}

extern "C" void kernel_launch(void* const* d_in, const int* in_sizes, int n_in,
                              void* d_out, int out_size, void* d_ws, size_t ws_size,
                              hipStream_t stream)
{
    (void)in_sizes; (void)n_in; (void)out_size; (void)ws_size;
    const float* x       = (const float*)d_in[0];
    const float* query   = (const float*)d_in[1];
    const float* key_w   = (const float*)d_in[2];
    const float* key_b   = (const float*)d_in[3];
    const float* val_w   = (const float*)d_in[4];
    const float* val_b   = (const float*)d_in[5];
    const float* query_w = (const float*)d_in[6];
    const float* query_b = (const float*)d_in[7];
    const float* up_w    = (const float*)d_in[8];
    const float* up_b    = (const float*)d_in[9];
    const float* scaling = (const float*)d_in[10];
    float* out = (float*)d_out;

    const size_t TEN = (size_t)NB * NN * CO;   // 4,194,304 elements
    u8* kT  = (u8*)d_ws;                       // [B,N,Co] fp8 (key proj = attn Q)
    u8* qT  = kT + TEN;                        // [B,N,Co] fp8 (query proj = attn K)
    u8* vT2 = qT + TEN;                        // [B,Co,N] fp8
    __bf16* Opart = (__bf16*)(vT2 + TEN);      // [SPLIT,B,N,Co] bf16
    float*  lbuf  = (float*)(Opart + (size_t)SPLIT * TEN);  // [SPLIT,B,N]

    dim3 blk(256);
    proj3_kernel<<<dim3(NN / 128, CO / 64, NB), blk, 0, stream>>>(
        x, query, key_w, key_b, val_w, val_b, query_w, query_b, kT, vT2, qT);
    attn_kernel<<<dim3(NN / 128, SPLIT, NB), blk, 0, stream>>>(kT, qT, vT2, Opart, lbuf);
    up_kernel<<<dim3(NN / 128, CI / 128, NB), blk, 0, stream>>>(
        Opart, lbuf, x, up_w, up_b, scaling, out);
}